// Round 1
// baseline (795.464 us; speedup 1.0000x reference)
//
#include <hip/hip_runtime.h>
#include <hip/hip_cooperative_groups.h>
#include <stdint.h>
#include <math.h>

namespace cg = cooperative_groups;

// ---------------------------------------------------------------------------
// PathIntegration: h = relu(actions@w1+b1); trans = (h@w2+b2) -> [B,T,D,D]
// s_{t+1} = l2norm(relu(s_t @ trans_t)); output ys[B,T,D] (f32)
// B=32 T=512 A=64 H=256 D=128
// Round 9: persistent cooperative kernel. The former per-chunk kernel
// relaunches (nch+1 of them, ~33 at Tc=16) are replaced by ONE
// hipLaunchCooperativeKernel with grid.sync() between chunk phases.
// Rec ring (depth 4, manual vmcnt schedule) and gemm tile loop are
// unchanged from round 8. grid.sync provides the device-scope release/
// acquire the kernel boundary used to provide for the tbuf handoff.
// Grid = 256 exactly -> 1 block/CU -> cooperative co-residency guaranteed.
// ---------------------------------------------------------------------------

typedef _Float16 f16x8 __attribute__((ext_vector_type(8)));
typedef float    f32x4 __attribute__((ext_vector_type(4)));

#define B_  32
#define T_  512
#define A_  64
#define H_  256
#define D_  128
#define N_  (D_ * D_)      // 16384
#define M_  (B_ * T_)      // 16384

__device__ inline void glds(const void* g, void* l) {
  __builtin_amdgcn_global_load_lds(
      (__attribute__((address_space(1))) void*)g,
      (__attribute__((address_space(3))) void*)l, 16, 0, 0);
}

// ---------------- w2 cast + transpose + fragment-direct PERMUTE --------------
// orig col n of w2 -> T entry (i=n>>7, j=n&127). New position (elements):
// p = (j>>4)<<11 | (i>>5)<<9 | ((i>>3)&3)<<7 | (j&15)<<3 | (i&7)
// so per (b,t) the 32 KB step-slab is wave-major, frag-major, lane-direct:
// byte ofs = w*4096 + f*1024 + lane*16 holds B-frag f of wave w.
__global__ __launch_bounds__(256) void w2cast_kernel(const float* __restrict__ w2,
                                                     _Float16* __restrict__ w2t) {
  __shared__ float tile[64][65];
  const int t = threadIdx.x;
  const int n0 = blockIdx.x * 64, k0 = blockIdx.y * 64;
  const int nn = t & 63, kg = t >> 6;
  #pragma unroll
  for (int r = 0; r < 16; ++r) {
    int k = kg * 16 + r;
    tile[k][nn] = w2[(size_t)(k0 + k) * N_ + n0 + nn];
  }
  __syncthreads();
  const int kk = t & 63, ng = t >> 6;
  #pragma unroll
  for (int r = 0; r < 16; ++r) {
    int n = ng * 16 + r;
    int ngl = n0 + n;
    int i = ngl >> 7, j = ngl & 127;
    int p = ((j >> 4) << 11) | ((i >> 5) << 9) | (((i >> 3) & 3) << 7)
          | ((j & 15) << 3) | (i & 7);
    w2t[(size_t)p * H_ + k0 + kk] = (_Float16)tile[kk][n];
  }
}

// ---------------- h = relu(actions@w1+b1) fp16 [16384][256] ------------------
__global__ __launch_bounds__(256) void h_kernel(const float* __restrict__ actions,
                                                const float* __restrict__ w1,
                                                const float* __restrict__ b1,
                                                _Float16* __restrict__ h16) {
  __shared__ float w1s[32 * 256];
  __shared__ float acts[32 * 64];
  const int t = threadIdx.x;
  const size_t row0 = (size_t)blockIdx.x * 32;

  #pragma unroll
  for (int i = 0; i < 8; ++i) acts[t + i * 256] = actions[row0 * A_ + t + i * 256];

  float acc[32];
  float bj = b1[t];
  #pragma unroll
  for (int r = 0; r < 32; ++r) acc[r] = bj;

  for (int half = 0; half < 2; ++half) {
    __syncthreads();
    #pragma unroll
    for (int i = 0; i < 32; ++i) w1s[t + i * 256] = w1[half * 32 * 256 + t + i * 256];
    __syncthreads();
    #pragma unroll
    for (int r = 0; r < 32; ++r) {
      float a = acc[r];
      #pragma unroll
      for (int k = 0; k < 32; ++k)
        a += acts[r * 64 + half * 32 + k] * w1s[k * 256 + t];
      acc[r] = a;
    }
  }
  #pragma unroll
  for (int r = 0; r < 32; ++r)
    h16[(row0 + r) * H_ + t] = (_Float16)fmaxf(acc[r], 0.f);
}

// ---------------- fused persistent: rec blocks 0..31, gemm 32..255 -----------
__global__ __launch_bounds__(512, 2) void fused_kernel(
    const _Float16* __restrict__ h16, const _Float16* __restrict__ w2t,
    const float* __restrict__ b2, _Float16* __restrict__ tbuf0,
    _Float16* __restrict__ tbuf1, const float* __restrict__ init_s,
    float* __restrict__ out, float* __restrict__ dummyws,
    int Tc, int tcs, int nch) {

  // layout: gemm uses [0,32768). rec: sb0 @32768 (256B), sb1 @33024 (256B),
  // red @33280 (32B).
  __shared__ __align__(16) char smem[33536];
  const int tid  = threadIdx.x;
  const int lane = tid & 63;
  const int w    = tid >> 6;
  cg::grid_group grid = cg::this_grid();

  for (int c = -1; c < nch; ++c) {
    if (blockIdx.x < 32) {
      // ======================= recurrence block (chunk c) ===================
      if (c >= 0) {
        const char* trans = (const char*)((c & 1) ? tbuf1 : tbuf0);
        const int b  = blockIdx.x;
        const int t0 = c * Tc;
        const int n16 = lane & 15, q = lane >> 4;
        const int col = w * 16 + n16;
        const int Tcm1 = Tc - 1;
        float* red = (float*)(smem + 33280);
        _Float16* sb0p = (_Float16*)(smem + 32768);

        // ---- init s_0 (normalized carry) into sb0 ----
        float v0 = 0.f;
        if (tid < 128) {
          v0 = (t0 == 0) ? init_s[tid] : out[((size_t)b * T_ + t0 - 1) * D_ + tid];
          float ss = v0 * v0;
          #pragma unroll
          for (int off = 32; off > 0; off >>= 1) ss += __shfl_xor(ss, off);
          if (lane == 0) red[w] = ss;
        }
        __syncthreads();
        if (tid < 128) {
          float inv0 = 1.f / fmaxf(sqrtf(red[0] + red[1]), 1e-12f);
          sb0p[tid] = (_Float16)(v0 * inv0);
        }
        __syncthreads();

        float uprev = (float)sb0p[col];   // chunk-boundary rewrite is a no-op

        // addresses
        const unsigned sbase = (unsigned)(size_t)(__attribute__((address_space(3))) char*)smem;
        const unsigned aA0 = sbase + 32768 + q * 16;   // step par 0 reads sb0
        const unsigned aA1 = sbase + 33024 + q * 16;   // step par 1 reads sb1
        const unsigned aW0 = sbase + 33024 + col * 2;  // step par 0 writes sb1
        const unsigned aW1 = sbase + 32768 + col * 2;  // step par 1 writes sb0
        const char* Gw = trans + (size_t)b * Tc * 32768 + w * 4096 + lane * 16;
        float* outb = out + (size_t)b * T_ * D_ + col;
        float* dsink = dummyws + blockIdx.x * 128 + col;

        // ---- warmup: ring slots 0..3 <- slabs 0..3 (16 loads outstanding) --
        f16x8 ring[4][4];
#define LDSLOT(S, P)                                                          \
        asm volatile("global_load_dwordx4 %0, %4, off\n\t"                    \
                     "global_load_dwordx4 %1, %4, off offset:1024\n\t"        \
                     "global_load_dwordx4 %2, %4, off offset:2048\n\t"        \
                     "global_load_dwordx4 %3, %4, off offset:3072"            \
                     : "=v"(ring[S][0]), "=v"(ring[S][1]),                    \
                       "=v"(ring[S][2]), "=v"(ring[S][3])                     \
                     : "v"(P) : "memory")
        LDSLOT(0, Gw + 0 * 32768);
        LDSLOT(1, Gw + 1 * 32768);
        LDSLOT(2, Gw + 2 * 32768);
        LDSLOT(3, Gw + 3 * 32768);

        const f32x4 zf = {0.f, 0.f, 0.f, 0.f};

#define STEP(TT, PAR, SPAR, WAITN)                                            \
        {                                                                     \
          const int tt = (TT);                                                \
          f16x8 A0, A1, A2, A3;                                               \
          asm volatile(                                                       \
            "s_waitcnt vmcnt(" #WAITN ")\n\t"                                 \
            "ds_read_b128 %0, %8 offset:0\n\t"                                \
            "ds_read_b128 %1, %8 offset:64\n\t"                               \
            "ds_read_b128 %2, %8 offset:128\n\t"                              \
            "ds_read_b128 %3, %8 offset:192\n\t"                              \
            "s_waitcnt lgkmcnt(0)"                                            \
            : "=v"(A0), "=v"(A1), "=v"(A2), "=v"(A3),                         \
              "+v"(ring[PAR][0]), "+v"(ring[PAR][1]),                         \
              "+v"(ring[PAR][2]), "+v"(ring[PAR][3])                          \
            : "v"(aA##SPAR) : "memory");                                      \
          f32x4 c0 = __builtin_amdgcn_mfma_f32_16x16x32_f16(A0, ring[PAR][0], zf, 0, 0, 0); \
          f32x4 c1 = __builtin_amdgcn_mfma_f32_16x16x32_f16(A1, ring[PAR][1], zf, 0, 0, 0); \
          f32x4 c2 = __builtin_amdgcn_mfma_f32_16x16x32_f16(A2, ring[PAR][2], zf, 0, 0, 0); \
          f32x4 c3 = __builtin_amdgcn_mfma_f32_16x16x32_f16(A3, ring[PAR][3], zf, 0, 0, 0); \
          f32x4 cs = __builtin_amdgcn_mfma_f32_16x16x32_f16(A0, A0, zf, 0, 0, 0); \
          cs = __builtin_amdgcn_mfma_f32_16x16x32_f16(A1, A1, cs, 0, 0, 0);   \
          cs = __builtin_amdgcn_mfma_f32_16x16x32_f16(A2, A2, cs, 0, 0, 0);   \
          cs = __builtin_amdgcn_mfma_f32_16x16x32_f16(A3, A3, cs, 0, 0, 0);   \
          const char* gd = Gw + (size_t)((tt + 4) & Tcm1) * 32768;            \
          LDSLOT(PAR, gd);                                                    \
          float ssp = cs[0];                                                  \
          float inv = 1.f / fmaxf(sqrtf(ssp), 1e-12f);                        \
          float y = c0[0] + c1[0] + c2[0] + c3[0];                            \
          float un = fmaxf(y, 0.f) * inv;                                     \
          float o = uprev * inv;                                              \
          uprev = un;                                                         \
          _Float16 hv = (_Float16)un;                                         \
          const int gt = t0 + tt;                                             \
          float* gp = (gt > 0) ? (outb + (size_t)(gt - 1) * D_) : dsink;      \
          asm volatile("ds_write_b16 %0, %1\n\t"                              \
                       "global_store_dword %2, %3, off"                       \
                       :: "v"(aW##SPAR), "v"(hv), "v"(gp), "v"(o) : "memory");\
          asm volatile("s_waitcnt lgkmcnt(0)\n\ts_barrier" ::: "memory");     \
        }

        STEP(0, 0, 0, 12)
        STEP(1, 1, 1, 13)
        STEP(2, 2, 0, 14)
        STEP(3, 3, 1, 15)
        for (int tt0 = 4; tt0 < Tc; tt0 += 4) {
          STEP(tt0,     0, 0, 16)
          STEP(tt0 + 1, 1, 1, 16)
          STEP(tt0 + 2, 2, 0, 16)
          STEP(tt0 + 3, 3, 1, 16)
        }
#undef STEP
#undef LDSLOT
        asm volatile("s_waitcnt vmcnt(0)" ::: "memory");

        // ---- epilogue: final norm (state in sb0; Tc mult of 4), write Tc-1 --
        {
          float x = 0.f;
          if (lane < 16) x = (float)((_Float16*)(smem + 32768))[col];
          float ss2 = x * x;
          ss2 += __shfl_xor(ss2, 1);
          ss2 += __shfl_xor(ss2, 2);
          ss2 += __shfl_xor(ss2, 4);
          ss2 += __shfl_xor(ss2, 8);
          if (lane == 0) red[w] = ss2;
          __syncthreads();
          float tot = 0.f;
          #pragma unroll
          for (int g = 0; g < 8; ++g) tot += red[g];
          float inv = 1.f / fmaxf(sqrtf(tot), 1e-12f);
          if (lane < 16) outb[(size_t)(t0 + Tc - 1) * D_] = uprev * inv;
        }
      }
    } else {
      // ======================= persistent gemm (chunk c+1) ==================
      const int g = c + 1;
      if (g < nch) {
        _Float16* trans = (g & 1) ? tbuf1 : tbuf0;
        const int t0g = g * Tc;

        _Float16* smA = (_Float16*)smem;            // 256x32 fp16 = 16 KB
        _Float16* smB = (_Float16*)(smem + 16384);  // 16 KB

        const int wm = w >> 2, wn = w & 3;          // 2x4 wave grid: 128m x 64n
        const int fm = lane & 15, fq = lane >> 4;
        const f32x4 zero = {0.f, 0.f, 0.f, 0.f};

        const int cA0 = tid, cA1 = tid + 512;
        const int rA0 = cA0 >> 2, kA0 = cA0 & 3;
        const int rA1 = cA1 >> 2, kA1 = cA1 & 3;

        const int mtiles = (B_ * Tc) >> 8;
        const int ntot = mtiles * 64;
        for (int tile = (int)blockIdx.x - 32; tile < ntot; tile += 224) {
          const int bn = tile & 63;
          const int bm = tile >> 6;

          const int mc0 = bm * 256 + rA0, mc1 = bm * 256 + rA1;
          const int bb0 = mc0 >> tcs, bb1 = mc1 >> tcs;
          const _Float16* gA0 = h16 + ((size_t)bb0 * T_ + t0g + (mc0 & (Tc - 1))) * H_ + kA0 * 8;
          const _Float16* gA1 = h16 + ((size_t)bb1 * T_ + t0g + (mc1 & (Tc - 1))) * H_ + kA1 * 8;
          const _Float16* gB0 = w2t + ((size_t)bn * 256 + rA0) * H_ + kA0 * 8;
          const _Float16* gB1 = w2t + ((size_t)bn * 256 + rA1) * H_ + kA1 * 8;
          _Float16* lA0 = &smA[cA0 * 8];
          _Float16* lA1 = &smA[cA1 * 8];
          _Float16* lB0 = &smB[cA0 * 8];
          _Float16* lB1 = &smB[cA1 * 8];

          f32x4 acc[8][4];
          #pragma unroll
          for (int i = 0; i < 8; ++i)
            #pragma unroll
            for (int j = 0; j < 4; ++j) acc[i][j] = zero;

          for (int kt = 0; kt < H_ / 32; ++kt) {
            __syncthreads();
            glds(gA0 + kt * 32, lA0);
            glds(gA1 + kt * 32, lA1);
            glds(gB0 + kt * 32, lB0);
            glds(gB1 + kt * 32, lB1);
            __syncthreads();
            f16x8 af[8], bf[4];
            #pragma unroll
            for (int mt = 0; mt < 8; ++mt)
              af[mt] = *(const f16x8*)&smA[(wm * 128 + mt * 16 + fm) * 32 + fq * 8];
            #pragma unroll
            for (int nt = 0; nt < 4; ++nt)
              bf[nt] = *(const f16x8*)&smB[(wn * 64 + nt * 16 + fm) * 32 + fq * 8];
            #pragma unroll
            for (int mt = 0; mt < 8; ++mt)
              #pragma unroll
              for (int nt = 0; nt < 4; ++nt)
                acc[mt][nt] = __builtin_amdgcn_mfma_f32_16x16x32_f16(af[mt], bf[nt], acc[mt][nt], 0, 0, 0);
          }

          // epilogue: col is permuted p; invert for b2
          #pragma unroll
          for (int nt = 0; nt < 4; ++nt) {
            int col = bn * 256 + wn * 64 + nt * 16 + fm;
            int pw = col >> 11, pf = (col >> 9) & 3, pq = (col >> 7) & 3;
            int pn = (col >> 3) & 15, pr = col & 7;
            int ii = pf * 32 + pq * 8 + pr, jj = pw * 16 + pn;
            float bias = b2[ii * 128 + jj];
            #pragma unroll
            for (int mt = 0; mt < 8; ++mt) {
              #pragma unroll
              for (int r = 0; r < 4; ++r) {
                long row = bm * 256 + wm * 128 + mt * 16 + fq * 4 + r;
                trans[row * (long)N_ + col] = (_Float16)(acc[mt][nt][r] + bias);
              }
            }
          }
          __syncthreads();
        }
      }
    }
    // chunk handoff: device-scope barrier (replaces the kernel relaunch)
    if (c < nch - 1) grid.sync();
  }
}

// ---------------------------------------------------------------------------
extern "C" void kernel_launch(void* const* d_in, const int* in_sizes, int n_in,
                              void* d_out, int out_size, void* d_ws, size_t ws_size,
                              hipStream_t stream) {
  const float* actions = (const float*)d_in[0];   // [32,512,64]
  const float* init_s  = (const float*)d_in[1];   // [128]
  const float* w1      = (const float*)d_in[2];   // [64,256]
  const float* b1      = (const float*)d_in[3];   // [256]
  const float* w2      = (const float*)d_in[4];   // [256,16384]
  const float* b2      = (const float*)d_in[5];   // [16384]
  float* out = (float*)d_out;                     // [32,512,128]

  uint8_t* ws = (uint8_t*)d_ws;
  _Float16* w2t = (_Float16*)ws;                          // 8 MB (permuted rows)
  _Float16* h16 = (_Float16*)(ws + ((size_t)8 << 20));    // 8 MB
  const size_t trans_off = (size_t)16 << 20;

  // largest Tc whose double-buffered trans + 64KB sink fits
  int Tc = 16;
  const int cands[3] = {64, 32, 16};
  for (int i = 0; i < 3; ++i) {
    if (trans_off + 2 * ((size_t)cands[i] << 20) + 65536 <= ws_size) { Tc = cands[i]; break; }
  }
  const int tcs = __builtin_ctz(Tc);
  _Float16* tbuf0 = (_Float16*)(ws + trans_off);
  _Float16* tbuf1 = (_Float16*)(ws + trans_off + ((size_t)Tc << 20));
  float* dummyws = (float*)(ws + trans_off + 2 * ((size_t)Tc << 20));

  w2cast_kernel<<<dim3(N_ / 64, 4), 256, 0, stream>>>(w2, w2t);
  h_kernel<<<M_ / 32, 256, 0, stream>>>(actions, w1, b1, h16);

  int nch = T_ / Tc;
  int Tc_a = Tc, tcs_a = tcs, nch_a = nch;
  void* kargs[] = {
    (void*)&h16, (void*)&w2t, (void*)&b2, (void*)&tbuf0, (void*)&tbuf1,
    (void*)&init_s, (void*)&out, (void*)&dummyws,
    (void*)&Tc_a, (void*)&tcs_a, (void*)&nch_a
  };
  hipLaunchCooperativeKernel((const void*)fused_kernel, dim3(256), dim3(512),
                             kargs, 0, stream);
}

// Round 2
// 683.162 us; speedup vs baseline: 1.1644x; 1.1644x over previous
//
#include <hip/hip_runtime.h>
#include <stdint.h>
#include <math.h>

// ---------------------------------------------------------------------------
// PathIntegration: h = relu(actions@w1+b1); trans = (h@w2+b2) -> [B,T,D,D]
// s_{t+1} = l2norm(relu(s_t @ trans_t)); output ys[B,T,D] (f32)
// B=32 T=512 A=64 H=256 D=128
// Round 10: flag-based producer-consumer pipeline (single regular launch).
// grid.sync (round 9, -270us regression) and per-chunk relaunches (round 8)
// replaced by per-rowgroup ready counters + recDone back-pressure:
//   gemm tile done -> syncthreads (drain stores) -> threadfence (wbl2,
//   cross-XCD release) -> relaxed atomicAdd cnt[chunk][rowgroup]
//   rec waits cnt==64 (relaxed spin + acquire fence/buffer_inv: tbuf reused
//   every 2 chunks so stale-L2 invalidation is REQUIRED), consumes chunk,
//   vmcnt(0) + syncthreads -> relaxed atomicAdd recDone[c]
//   gemm entering chunk g>=2 waits recDone[g-2]==32 (double-buffer safety)
// rec state persists in LDS/regs across chunks (no per-chunk init/epilogue;
// boundary outputs come from next chunk's STEP(0) — same math as interior).
// Deadlock-free: chunks 0,1 unblocked; grid=256 -> all blocks co-resident.
// ---------------------------------------------------------------------------

typedef _Float16 f16x8 __attribute__((ext_vector_type(8)));
typedef float    f32x4 __attribute__((ext_vector_type(4)));

#define B_  32
#define T_  512
#define A_  64
#define H_  256
#define D_  128
#define N_  (D_ * D_)      // 16384
#define M_  (B_ * T_)      // 16384

__device__ inline void glds(const void* g, void* l) {
  __builtin_amdgcn_global_load_lds(
      (__attribute__((address_space(1))) void*)g,
      (__attribute__((address_space(3))) void*)l, 16, 0, 0);
}

// ---------------- w2 cast + transpose + fragment-direct PERMUTE --------------
// orig col n of w2 -> T entry (i=n>>7, j=n&127). New position (elements):
// p = (j>>4)<<11 | (i>>5)<<9 | ((i>>3)&3)<<7 | (j&15)<<3 | (i&7)
// so per (b,t) the 32 KB step-slab is wave-major, frag-major, lane-direct:
// byte ofs = w*4096 + f*1024 + lane*16 holds B-frag f of wave w.
// Also zeroes the pipeline flags (block (0,0)) — stream-ordered before fused.
__global__ __launch_bounds__(256) void w2cast_kernel(const float* __restrict__ w2,
                                                     _Float16* __restrict__ w2t,
                                                     unsigned* __restrict__ flags) {
  if (blockIdx.x == 0 && blockIdx.y == 0) {
    #pragma unroll
    for (int i = 0; i < 4; ++i) flags[threadIdx.x + i * 256] = 0u;
  }
  __shared__ float tile[64][65];
  const int t = threadIdx.x;
  const int n0 = blockIdx.x * 64, k0 = blockIdx.y * 64;
  const int nn = t & 63, kg = t >> 6;
  #pragma unroll
  for (int r = 0; r < 16; ++r) {
    int k = kg * 16 + r;
    tile[k][nn] = w2[(size_t)(k0 + k) * N_ + n0 + nn];
  }
  __syncthreads();
  const int kk = t & 63, ng = t >> 6;
  #pragma unroll
  for (int r = 0; r < 16; ++r) {
    int n = ng * 16 + r;
    int ngl = n0 + n;
    int i = ngl >> 7, j = ngl & 127;
    int p = ((j >> 4) << 11) | ((i >> 5) << 9) | (((i >> 3) & 3) << 7)
          | ((j & 15) << 3) | (i & 7);
    w2t[(size_t)p * H_ + k0 + kk] = (_Float16)tile[kk][n];
  }
}

// ---------------- h = relu(actions@w1+b1) fp16 [16384][256] ------------------
__global__ __launch_bounds__(256) void h_kernel(const float* __restrict__ actions,
                                                const float* __restrict__ w1,
                                                const float* __restrict__ b1,
                                                _Float16* __restrict__ h16) {
  __shared__ float w1s[32 * 256];
  __shared__ float acts[32 * 64];
  const int t = threadIdx.x;
  const size_t row0 = (size_t)blockIdx.x * 32;

  #pragma unroll
  for (int i = 0; i < 8; ++i) acts[t + i * 256] = actions[row0 * A_ + t + i * 256];

  float acc[32];
  float bj = b1[t];
  #pragma unroll
  for (int r = 0; r < 32; ++r) acc[r] = bj;

  for (int half = 0; half < 2; ++half) {
    __syncthreads();
    #pragma unroll
    for (int i = 0; i < 32; ++i) w1s[t + i * 256] = w1[half * 32 * 256 + t + i * 256];
    __syncthreads();
    #pragma unroll
    for (int r = 0; r < 32; ++r) {
      float a = acc[r];
      #pragma unroll
      for (int k = 0; k < 32; ++k)
        a += acts[r * 64 + half * 32 + k] * w1s[k * 256 + t];
      acc[r] = a;
    }
  }
  #pragma unroll
  for (int r = 0; r < 32; ++r)
    h16[(row0 + r) * H_ + t] = (_Float16)fmaxf(acc[r], 0.f);
}

// ---------------- fused pipeline: rec blocks 0..31, gemm 32..255 -------------
__global__ __launch_bounds__(512, 2) void fused_kernel(
    const _Float16* __restrict__ h16, const _Float16* __restrict__ w2t,
    const float* __restrict__ b2, _Float16* __restrict__ tbuf0,
    _Float16* __restrict__ tbuf1, const float* __restrict__ init_s,
    float* __restrict__ out, float* __restrict__ dummyws,
    unsigned* __restrict__ flags, int Tc, int tcs, int nch) {

  // layout: gemm uses [0,32768). rec: sb0 @32768 (256B), sb1 @33024 (256B),
  // red @33280 (32B).
  __shared__ __align__(16) char smem[33536];
  const int tid  = threadIdx.x;
  const int lane = tid & 63;
  const int w    = tid >> 6;
  const int MT   = 1 << (tcs - 3);       // row-groups (256-row tiles) per chunk

  if (blockIdx.x < 32) {
    // ======================= recurrence block ===============================
    const int b  = blockIdx.x;
    const int n16 = lane & 15, q = lane >> 4;
    const int col = w * 16 + n16;
    const int Tcm1 = Tc - 1;
    float* red = (float*)(smem + 33280);
    _Float16* sb0p = (_Float16*)(smem + 32768);

    // ---- init s_0 once (state persists across chunks afterwards) ----
    float v0 = 0.f;
    if (tid < 128) {
      v0 = init_s[tid];
      float ss = v0 * v0;
      #pragma unroll
      for (int off = 32; off > 0; off >>= 1) ss += __shfl_xor(ss, off);
      if (lane == 0) red[w] = ss;
    }
    __syncthreads();
    if (tid < 128) {
      float inv0 = 1.f / fmaxf(sqrtf(red[0] + red[1]), 1e-12f);
      sb0p[tid] = (_Float16)(v0 * inv0);
    }
    __syncthreads();
    float uprev = (float)sb0p[col];

    // addresses
    const unsigned sbase = (unsigned)(size_t)(__attribute__((address_space(3))) char*)smem;
    const unsigned aA0 = sbase + 32768 + q * 16;   // step par 0 reads sb0
    const unsigned aA1 = sbase + 33024 + q * 16;   // step par 1 reads sb1
    const unsigned aW0 = sbase + 33024 + col * 2;  // step par 0 writes sb1
    const unsigned aW1 = sbase + 32768 + col * 2;  // step par 1 writes sb0
    float* outb = out + (size_t)b * T_ * D_ + col;
    float* dsink = dummyws + b * 128 + col;
    const int grp = b >> (8 - tcs);

    f16x8 ring[4][4];
    const f32x4 zf = {0.f, 0.f, 0.f, 0.f};

#define LDSLOT(S, P)                                                          \
    asm volatile("global_load_dwordx4 %0, %4, off\n\t"                        \
                 "global_load_dwordx4 %1, %4, off offset:1024\n\t"            \
                 "global_load_dwordx4 %2, %4, off offset:2048\n\t"            \
                 "global_load_dwordx4 %3, %4, off offset:3072"                \
                 : "=v"(ring[S][0]), "=v"(ring[S][1]),                        \
                   "=v"(ring[S][2]), "=v"(ring[S][3])                         \
                 : "v"(P) : "memory")

#define STEP(TT, PAR, SPAR, WAITN)                                            \
    {                                                                         \
      const int tt = (TT);                                                    \
      f16x8 A0, A1, A2, A3;                                                   \
      asm volatile(                                                           \
        "s_waitcnt vmcnt(" #WAITN ")\n\t"                                     \
        "ds_read_b128 %0, %8 offset:0\n\t"                                    \
        "ds_read_b128 %1, %8 offset:64\n\t"                                   \
        "ds_read_b128 %2, %8 offset:128\n\t"                                  \
        "ds_read_b128 %3, %8 offset:192\n\t"                                  \
        "s_waitcnt lgkmcnt(0)"                                                \
        : "=v"(A0), "=v"(A1), "=v"(A2), "=v"(A3),                             \
          "+v"(ring[PAR][0]), "+v"(ring[PAR][1]),                             \
          "+v"(ring[PAR][2]), "+v"(ring[PAR][3])                              \
        : "v"(aA##SPAR) : "memory");                                          \
      f32x4 c0 = __builtin_amdgcn_mfma_f32_16x16x32_f16(A0, ring[PAR][0], zf, 0, 0, 0); \
      f32x4 c1 = __builtin_amdgcn_mfma_f32_16x16x32_f16(A1, ring[PAR][1], zf, 0, 0, 0); \
      f32x4 c2 = __builtin_amdgcn_mfma_f32_16x16x32_f16(A2, ring[PAR][2], zf, 0, 0, 0); \
      f32x4 c3 = __builtin_amdgcn_mfma_f32_16x16x32_f16(A3, ring[PAR][3], zf, 0, 0, 0); \
      f32x4 cs = __builtin_amdgcn_mfma_f32_16x16x32_f16(A0, A0, zf, 0, 0, 0); \
      cs = __builtin_amdgcn_mfma_f32_16x16x32_f16(A1, A1, cs, 0, 0, 0);       \
      cs = __builtin_amdgcn_mfma_f32_16x16x32_f16(A2, A2, cs, 0, 0, 0);       \
      cs = __builtin_amdgcn_mfma_f32_16x16x32_f16(A3, A3, cs, 0, 0, 0);       \
      const char* gd = Gw + (size_t)((tt + 4) & Tcm1) * 32768;                \
      LDSLOT(PAR, gd);                                                        \
      float ssp = cs[0];                                                      \
      float inv = 1.f / fmaxf(sqrtf(ssp), 1e-12f);                            \
      float y = c0[0] + c1[0] + c2[0] + c3[0];                                \
      float un = fmaxf(y, 0.f) * inv;                                         \
      float o = uprev * inv;                                                  \
      uprev = un;                                                             \
      _Float16 hv = (_Float16)un;                                             \
      const int gt = t0 + tt;                                                 \
      float* gp = (gt > 0) ? (outb + (size_t)(gt - 1) * D_) : dsink;          \
      asm volatile("ds_write_b16 %0, %1\n\t"                                  \
                   "global_store_dword %2, %3, off"                           \
                   :: "v"(aW##SPAR), "v"(hv), "v"(gp), "v"(o) : "memory");    \
      asm volatile("s_waitcnt lgkmcnt(0)\n\ts_barrier" ::: "memory");         \
    }

    for (int c = 0; c < nch; ++c) {
      // wait for this batch's row-group of chunk c (64 column tiles)
      if (tid == 0) {
        while (__hip_atomic_load(&flags[c * MT + grp], __ATOMIC_RELAXED,
                                 __HIP_MEMORY_SCOPE_AGENT) < 64u)
          __builtin_amdgcn_s_sleep(8);
        __threadfence();   // acquire: invalidate stale L1/L2 (tbuf reused)
      }
      __syncthreads();

      const char* trans = (const char*)((c & 1) ? tbuf1 : tbuf0);
      const char* Gw = trans + (size_t)b * Tc * 32768 + w * 4096 + lane * 16;
      const int t0 = c * Tc;

      // ---- warmup: ring slots 0..3 <- slabs 0..3 (16 loads outstanding) ----
      LDSLOT(0, Gw + 0 * 32768);
      LDSLOT(1, Gw + 1 * 32768);
      LDSLOT(2, Gw + 2 * 32768);
      LDSLOT(3, Gw + 3 * 32768);

      STEP(0, 0, 0, 12)
      STEP(1, 1, 1, 13)
      STEP(2, 2, 0, 14)
      STEP(3, 3, 1, 15)
      for (int tt0 = 4; tt0 < Tc; tt0 += 4) {
        STEP(tt0,     0, 0, 16)
        STEP(tt0 + 1, 1, 1, 16)
        STEP(tt0 + 2, 2, 0, 16)
        STEP(tt0 + 3, 3, 1, 16)
      }
      asm volatile("s_waitcnt vmcnt(0)" ::: "memory");
      __syncthreads();   // all waves' loads drained before releasing buffer
      if (tid == 0)
        __hip_atomic_fetch_add(&flags[512 + c], 1u, __ATOMIC_RELAXED,
                               __HIP_MEMORY_SCOPE_AGENT);
    }
#undef STEP
#undef LDSLOT

    // ---- final epilogue: state in sb0; write out[T-1] ----
    {
      float x = 0.f;
      if (lane < 16) x = (float)((_Float16*)(smem + 32768))[col];
      float ss2 = x * x;
      ss2 += __shfl_xor(ss2, 1);
      ss2 += __shfl_xor(ss2, 2);
      ss2 += __shfl_xor(ss2, 4);
      ss2 += __shfl_xor(ss2, 8);
      if (lane == 0) red[w] = ss2;
      __syncthreads();
      float tot = 0.f;
      #pragma unroll
      for (int g = 0; g < 8; ++g) tot += red[g];
      float inv = 1.f / fmaxf(sqrtf(tot), 1e-12f);
      if (lane < 16) outb[(size_t)(T_ - 1) * D_] = uprev * inv;
    }
  } else {
    // ======================= streaming gemm producer ========================
    _Float16* smA = (_Float16*)smem;            // 256x32 fp16 = 16 KB
    _Float16* smB = (_Float16*)(smem + 16384);  // 16 KB

    const int wm = w >> 2, wn = w & 3;          // 2x4 wave grid: 128m x 64n
    const int fm = lane & 15, fq = lane >> 4;
    const f32x4 zero = {0.f, 0.f, 0.f, 0.f};

    const int cA0 = tid, cA1 = tid + 512;
    const int rA0 = cA0 >> 2, kA0 = cA0 & 3;
    const int rA1 = cA1 >> 2, kA1 = cA1 & 3;

    const int lnt = tcs + 3;                    // log2(tiles per chunk)
    const int TOT = nch << lnt;                 // total tiles (4096)

    for (int job = (int)blockIdx.x - 32; job < TOT; job += 224) {
      const int g    = job >> lnt;
      const int tile = job & ((1 << lnt) - 1);
      const int bn = tile & 63;
      const int bm = tile >> 6;

      // back-pressure: chunk g reuses buffer of chunk g-2
      if (g >= 2) {
        if (tid == 0) {
          while (__hip_atomic_load(&flags[512 + g - 2], __ATOMIC_RELAXED,
                                   __HIP_MEMORY_SCOPE_AGENT) < 32u)
            __builtin_amdgcn_s_sleep(8);
        }
        __syncthreads();
      }

      _Float16* trans = (g & 1) ? tbuf1 : tbuf0;
      const int t0g = g * Tc;

      const int mc0 = bm * 256 + rA0, mc1 = bm * 256 + rA1;
      const int bb0 = mc0 >> tcs, bb1 = mc1 >> tcs;
      const _Float16* gA0 = h16 + ((size_t)bb0 * T_ + t0g + (mc0 & (Tc - 1))) * H_ + kA0 * 8;
      const _Float16* gA1 = h16 + ((size_t)bb1 * T_ + t0g + (mc1 & (Tc - 1))) * H_ + kA1 * 8;
      const _Float16* gB0 = w2t + ((size_t)bn * 256 + rA0) * H_ + kA0 * 8;
      const _Float16* gB1 = w2t + ((size_t)bn * 256 + rA1) * H_ + kA1 * 8;
      _Float16* lA0 = &smA[cA0 * 8];
      _Float16* lA1 = &smA[cA1 * 8];
      _Float16* lB0 = &smB[cA0 * 8];
      _Float16* lB1 = &smB[cA1 * 8];

      f32x4 acc[8][4];
      #pragma unroll
      for (int i = 0; i < 8; ++i)
        #pragma unroll
        for (int j = 0; j < 4; ++j) acc[i][j] = zero;

      for (int kt = 0; kt < H_ / 32; ++kt) {
        __syncthreads();
        glds(gA0 + kt * 32, lA0);
        glds(gA1 + kt * 32, lA1);
        glds(gB0 + kt * 32, lB0);
        glds(gB1 + kt * 32, lB1);
        __syncthreads();
        f16x8 af[8], bf[4];
        #pragma unroll
        for (int mt = 0; mt < 8; ++mt)
          af[mt] = *(const f16x8*)&smA[(wm * 128 + mt * 16 + fm) * 32 + fq * 8];
        #pragma unroll
        for (int nt = 0; nt < 4; ++nt)
          bf[nt] = *(const f16x8*)&smB[(wn * 64 + nt * 16 + fm) * 32 + fq * 8];
        #pragma unroll
        for (int mt = 0; mt < 8; ++mt)
          #pragma unroll
          for (int nt = 0; nt < 4; ++nt)
            acc[mt][nt] = __builtin_amdgcn_mfma_f32_16x16x32_f16(af[mt], bf[nt], acc[mt][nt], 0, 0, 0);
      }

      // epilogue: col is permuted p; invert for b2
      #pragma unroll
      for (int nt = 0; nt < 4; ++nt) {
        int col = bn * 256 + wn * 64 + nt * 16 + fm;
        int pw = col >> 11, pf = (col >> 9) & 3, pq = (col >> 7) & 3;
        int pn = (col >> 3) & 15, pr = col & 7;
        int ii = pf * 32 + pq * 8 + pr, jj = pw * 16 + pn;
        float bias = b2[ii * 128 + jj];
        #pragma unroll
        for (int mt = 0; mt < 8; ++mt) {
          #pragma unroll
          for (int r = 0; r < 4; ++r) {
            long row = bm * 256 + wm * 128 + mt * 16 + fq * 4 + r;
            trans[row * (long)N_ + col] = (_Float16)(acc[mt][nt][r] + bias);
          }
        }
      }
      // release: syncthreads drains every wave's stores (vmcnt(0) before
      // s_barrier), then tid0 wbl2 + relaxed add on the rowgroup counter
      __syncthreads();
      if (tid == 0) {
        __threadfence();
        __hip_atomic_fetch_add(&flags[g * MT + bm], 1u, __ATOMIC_RELAXED,
                               __HIP_MEMORY_SCOPE_AGENT);
      }
    }
  }
}

// ---------------------------------------------------------------------------
extern "C" void kernel_launch(void* const* d_in, const int* in_sizes, int n_in,
                              void* d_out, int out_size, void* d_ws, size_t ws_size,
                              hipStream_t stream) {
  const float* actions = (const float*)d_in[0];   // [32,512,64]
  const float* init_s  = (const float*)d_in[1];   // [128]
  const float* w1      = (const float*)d_in[2];   // [64,256]
  const float* b1      = (const float*)d_in[3];   // [256]
  const float* w2      = (const float*)d_in[4];   // [256,16384]
  const float* b2      = (const float*)d_in[5];   // [16384]
  float* out = (float*)d_out;                     // [32,512,128]

  uint8_t* ws = (uint8_t*)d_ws;
  _Float16* w2t = (_Float16*)ws;                          // 8 MB (permuted rows)
  _Float16* h16 = (_Float16*)(ws + ((size_t)8 << 20));    // 8 MB
  const size_t trans_off = (size_t)16 << 20;

  // largest Tc whose double-buffered trans + 64KB sink + 4KB flags fits
  int Tc = 16;
  const int cands[3] = {64, 32, 16};
  for (int i = 0; i < 3; ++i) {
    if (trans_off + 2 * ((size_t)cands[i] << 20) + 65536 + 4096 <= ws_size) {
      Tc = cands[i];
      break;
    }
  }
  const int tcs = __builtin_ctz(Tc);
  _Float16* tbuf0 = (_Float16*)(ws + trans_off);
  _Float16* tbuf1 = (_Float16*)(ws + trans_off + ((size_t)Tc << 20));
  float* dummyws = (float*)(ws + trans_off + 2 * ((size_t)Tc << 20));
  unsigned* flags = (unsigned*)(ws + trans_off + 2 * ((size_t)Tc << 20) + 65536);

  w2cast_kernel<<<dim3(N_ / 64, 4), 256, 0, stream>>>(w2, w2t, flags);
  h_kernel<<<M_ / 32, 256, 0, stream>>>(actions, w1, b1, h16);

  const int nch = T_ / Tc;
  fused_kernel<<<256, 512, 0, stream>>>(h16, w2t, b2, tbuf0, tbuf1, init_s,
                                        out, dummyws, flags, Tc, tcs, nch);
}

// Round 4
// 665.711 us; speedup vs baseline: 1.1949x; 1.0262x over previous
//
#include <hip/hip_runtime.h>
#include <stdint.h>
#include <math.h>

// ---------------------------------------------------------------------------
// PathIntegration: h = relu(actions@w1+b1); trans = (h@w2+b2) -> [B,T,D,D]
// s_{t+1} = l2norm(relu(s_t @ trans_t)); output ys[B,T,D] (f32)
// B=32 T=512 A=64 H=256 D=128
// Round 12 = round 11 design with robustness fixes (r11 container died):
//  - smem exactly 65536 B (rec state overlaps gemm region; disjoint blocks)
//  - ws layout matching the r10-proven footprint: tbase @16MB, aux after ring
//  - b2p table dropped (bias decoded from b2 directly, hoisted pre-wait)
//  - full swizzle: k-slot staged s^((r>>1)&3), read fq^((fm>>1)&3) -> 2-way
// Core r11 ideas kept:
//  - gemm k-loop LDS double-buffer (glds(kt+1) under MFMA(kt); __syncthreads
//    implicit vmcnt(0) is the wait)
//  - swapped-operand MFMA epilogue: lane holds 4 consecutive cols -> f16x4
//    8B stores (4x fewer store insts)
//  - flag pipeline: gemm tile -> syncthreads -> tid0 {fence, atomicAdd
//    cnt[chunk][rowgroup]}; rec waits cnt==64, consumes, signals recDone;
//    gemm entering chunk g waits recDone[g-NB] before OVERWRITING (stores
//    gated, glds of h16/w2t not). Deadlock-free (min-stuck-chunk induction).
// ---------------------------------------------------------------------------

typedef _Float16 f16x8 __attribute__((ext_vector_type(8)));
typedef _Float16 f16x4 __attribute__((ext_vector_type(4)));
typedef float    f32x4 __attribute__((ext_vector_type(4)));

#define B_  32
#define T_  512
#define A_  64
#define H_  256
#define D_  128
#define N_  (D_ * D_)      // 16384
#define M_  (B_ * T_)      // 16384
#define TC_ 16
#define NCH_ (T_ / TC_)    // 32
#define MT_ 2              // 256-row groups per chunk
#define CHB ((size_t)TC_ << 20)   // 16 MB per chunk buffer

__device__ inline void glds(const void* g, void* l) {
  __builtin_amdgcn_global_load_lds(
      (__attribute__((address_space(1))) void*)g,
      (__attribute__((address_space(3))) void*)l, 16, 0, 0);
}

// ---------------- prep: w2 cast+transpose+permute, h, flags ------------------
// w2t permute: orig col n -> T entry (i=n>>7, j=n&127); position
// p = (j>>4)<<11 | (i>>5)<<9 | ((i>>3)&3)<<7 | (j&15)<<3 | (i&7)
// per (b,t) 32KB slab is wave-major, frag-major, lane-direct.
__global__ __launch_bounds__(256) void prep_kernel(
    const float* __restrict__ w2, _Float16* __restrict__ w2t,
    const float* __restrict__ actions, const float* __restrict__ w1,
    const float* __restrict__ b1, _Float16* __restrict__ h16,
    unsigned* __restrict__ flags) {
  __shared__ __align__(16) char psm[40960];
  const int t = threadIdx.x;
  if (blockIdx.x < 1024) {
    // ---------------- w2cast part ----------------
    if (blockIdx.x == 0) {
      #pragma unroll
      for (int i = 0; i < 4; ++i) flags[t + i * 256] = 0u;
    }
    float (*tile)[65] = (float(*)[65])psm;
    const int n0 = (blockIdx.x & 255) * 64, k0 = (blockIdx.x >> 8) * 64;
    const int nn = t & 63, kg = t >> 6;
    #pragma unroll
    for (int r = 0; r < 16; ++r) {
      int k = kg * 16 + r;
      tile[k][nn] = w2[(size_t)(k0 + k) * N_ + n0 + nn];
    }
    __syncthreads();
    const int kk = t & 63, ng = t >> 6;
    #pragma unroll
    for (int r = 0; r < 16; ++r) {
      int n = ng * 16 + r;
      int ngl = n0 + n;
      int i = ngl >> 7, j = ngl & 127;
      int p = ((j >> 4) << 11) | ((i >> 5) << 9) | (((i >> 3) & 3) << 7)
            | ((j & 15) << 3) | (i & 7);
      w2t[(size_t)p * H_ + k0 + kk] = (_Float16)tile[kk][n];
    }
  } else {
    // ---------------- h = relu(actions@w1+b1) ----------------
    float* w1s = (float*)psm;             // 32*256 f32
    float* acts = (float*)(psm + 32768);  // 32*64 f32
    const size_t row0 = (size_t)(blockIdx.x - 1024) * 32;

    #pragma unroll
    for (int i = 0; i < 8; ++i) acts[t + i * 256] = actions[row0 * A_ + t + i * 256];

    float acc[32];
    float bj = b1[t];
    #pragma unroll
    for (int r = 0; r < 32; ++r) acc[r] = bj;

    for (int half = 0; half < 2; ++half) {
      __syncthreads();
      #pragma unroll
      for (int i = 0; i < 32; ++i) w1s[t + i * 256] = w1[half * 32 * 256 + t + i * 256];
      __syncthreads();
      #pragma unroll
      for (int r = 0; r < 32; ++r) {
        float a = acc[r];
        #pragma unroll
        for (int k = 0; k < 32; ++k)
          a += acts[r * 64 + half * 32 + k] * w1s[k * 256 + t];
        acc[r] = a;
      }
    }
    #pragma unroll
    for (int r = 0; r < 32; ++r)
      h16[(row0 + r) * H_ + t] = (_Float16)fmaxf(acc[r], 0.f);
  }
}

// ---------------- fused pipeline: rec blocks 0..31, gemm 32..255 -------------
__global__ __launch_bounds__(512, 2) void fused_kernel(
    const _Float16* __restrict__ h16, const _Float16* __restrict__ w2t,
    const float* __restrict__ b2, _Float16* __restrict__ tbase,
    const float* __restrict__ init_s, float* __restrict__ out,
    float* __restrict__ dummyws, unsigned* __restrict__ flags, int NB) {

  // gemm blocks use all 64KB (A/B double-buffer). rec blocks (disjoint)
  // overlap: sb0 @0 (256B), sb1 @256 (256B), red @512 (32B).
  __shared__ __align__(16) char smem[65536];
  const int tid  = threadIdx.x;
  const int lane = tid & 63;
  const int w    = tid >> 6;

  if (blockIdx.x < 32) {
    // ======================= recurrence block ===============================
    const int b  = blockIdx.x;
    const int n16 = lane & 15, q = lane >> 4;
    const int col = w * 16 + n16;
    float* red = (float*)(smem + 512);
    _Float16* sb0p = (_Float16*)smem;

    // ---- init s_0 once (state persists in LDS/regs across chunks) ----
    float v0 = 0.f;
    if (tid < 128) {
      v0 = init_s[tid];
      float ss = v0 * v0;
      #pragma unroll
      for (int off = 32; off > 0; off >>= 1) ss += __shfl_xor(ss, off);
      if (lane == 0) red[w] = ss;
    }
    __syncthreads();
    if (tid < 128) {
      float inv0 = 1.f / fmaxf(sqrtf(red[0] + red[1]), 1e-12f);
      sb0p[tid] = (_Float16)(v0 * inv0);
    }
    __syncthreads();
    float uprev = (float)sb0p[col];

    const unsigned sbase = (unsigned)(size_t)(__attribute__((address_space(3))) char*)smem;
    const unsigned aA0 = sbase + 0   + q * 16;   // step par 0 reads sb0
    const unsigned aA1 = sbase + 256 + q * 16;   // step par 1 reads sb1
    const unsigned aW0 = sbase + 256 + col * 2;  // step par 0 writes sb1
    const unsigned aW1 = sbase + 0   + col * 2;  // step par 1 writes sb0
    float* outb = out + (size_t)b * T_ * D_ + col;
    float* dsink = dummyws + b * 128 + col;
    const int grp = b >> 4;

    f16x8 ring[4][4];
    const f32x4 zf = {0.f, 0.f, 0.f, 0.f};

#define LDSLOT(S, P)                                                          \
    asm volatile("global_load_dwordx4 %0, %4, off\n\t"                        \
                 "global_load_dwordx4 %1, %4, off offset:1024\n\t"            \
                 "global_load_dwordx4 %2, %4, off offset:2048\n\t"            \
                 "global_load_dwordx4 %3, %4, off offset:3072"                \
                 : "=v"(ring[S][0]), "=v"(ring[S][1]),                        \
                   "=v"(ring[S][2]), "=v"(ring[S][3])                         \
                 : "v"(P) : "memory")

#define STEP(TT, PAR, SPAR, WAITN)                                            \
    {                                                                         \
      const int tt = (TT);                                                    \
      f16x8 A0, A1, A2, A3;                                                   \
      asm volatile(                                                           \
        "s_waitcnt vmcnt(" #WAITN ")\n\t"                                     \
        "ds_read_b128 %0, %8 offset:0\n\t"                                    \
        "ds_read_b128 %1, %8 offset:64\n\t"                                   \
        "ds_read_b128 %2, %8 offset:128\n\t"                                  \
        "ds_read_b128 %3, %8 offset:192\n\t"                                  \
        "s_waitcnt lgkmcnt(0)"                                                \
        : "=v"(A0), "=v"(A1), "=v"(A2), "=v"(A3),                             \
          "+v"(ring[PAR][0]), "+v"(ring[PAR][1]),                             \
          "+v"(ring[PAR][2]), "+v"(ring[PAR][3])                              \
        : "v"(aA##SPAR) : "memory");                                          \
      f32x4 c0 = __builtin_amdgcn_mfma_f32_16x16x32_f16(A0, ring[PAR][0], zf, 0, 0, 0); \
      f32x4 c1 = __builtin_amdgcn_mfma_f32_16x16x32_f16(A1, ring[PAR][1], zf, 0, 0, 0); \
      f32x4 c2 = __builtin_amdgcn_mfma_f32_16x16x32_f16(A2, ring[PAR][2], zf, 0, 0, 0); \
      f32x4 c3 = __builtin_amdgcn_mfma_f32_16x16x32_f16(A3, ring[PAR][3], zf, 0, 0, 0); \
      f32x4 cs = __builtin_amdgcn_mfma_f32_16x16x32_f16(A0, A0, zf, 0, 0, 0); \
      cs = __builtin_amdgcn_mfma_f32_16x16x32_f16(A1, A1, cs, 0, 0, 0);       \
      cs = __builtin_amdgcn_mfma_f32_16x16x32_f16(A2, A2, cs, 0, 0, 0);       \
      cs = __builtin_amdgcn_mfma_f32_16x16x32_f16(A3, A3, cs, 0, 0, 0);       \
      const char* gd = Gw + (size_t)((tt + 4) & 15) * 32768;                  \
      LDSLOT(PAR, gd);                                                        \
      float ssp = cs[0];                                                      \
      float inv = 1.f / fmaxf(sqrtf(ssp), 1e-12f);                            \
      float y = c0[0] + c1[0] + c2[0] + c3[0];                                \
      float un = fmaxf(y, 0.f) * inv;                                         \
      float o = uprev * inv;                                                  \
      uprev = un;                                                             \
      _Float16 hv = (_Float16)un;                                             \
      const int gt = t0 + tt;                                                 \
      float* gp = (gt > 0) ? (outb + (size_t)(gt - 1) * D_) : dsink;          \
      asm volatile("ds_write_b16 %0, %1\n\t"                                  \
                   "global_store_dword %2, %3, off"                           \
                   :: "v"(aW##SPAR), "v"(hv), "v"(gp), "v"(o) : "memory");    \
      asm volatile("s_waitcnt lgkmcnt(0)\n\ts_barrier" ::: "memory");         \
    }

    for (int c = 0; c < NCH_; ++c) {
      if (tid == 0) {
        while (__hip_atomic_load(&flags[c * MT_ + grp], __ATOMIC_RELAXED,
                                 __HIP_MEMORY_SCOPE_AGENT) < 64u)
          __builtin_amdgcn_s_sleep(8);
        __threadfence();   // acquire: invalidate stale L1/L2 (buffer reused)
      }
      __syncthreads();

      const char* trans = (const char*)tbase + (size_t)(c % NB) * CHB;
      const char* Gw = trans + (size_t)b * TC_ * 32768 + w * 4096 + lane * 16;
      const int t0 = c * TC_;

      LDSLOT(0, Gw + 0 * 32768);
      LDSLOT(1, Gw + 1 * 32768);
      LDSLOT(2, Gw + 2 * 32768);
      LDSLOT(3, Gw + 3 * 32768);

      STEP(0, 0, 0, 12)
      STEP(1, 1, 1, 13)
      STEP(2, 2, 0, 14)
      STEP(3, 3, 1, 15)
      for (int tt0 = 4; tt0 < TC_; tt0 += 4) {
        STEP(tt0,     0, 0, 16)
        STEP(tt0 + 1, 1, 1, 16)
        STEP(tt0 + 2, 2, 0, 16)
        STEP(tt0 + 3, 3, 1, 16)
      }
      asm volatile("s_waitcnt vmcnt(0)" ::: "memory");
      __syncthreads();   // all waves' loads drained before releasing buffer
      if (tid == 0)
        __hip_atomic_fetch_add(&flags[512 + c], 1u, __ATOMIC_RELAXED,
                               __HIP_MEMORY_SCOPE_AGENT);
    }
#undef STEP
#undef LDSLOT

    // ---- final epilogue: state in sb0; write out[T-1] ----
    {
      float x = 0.f;
      if (lane < 16) x = (float)((_Float16*)smem)[col];
      float ss2 = x * x;
      ss2 += __shfl_xor(ss2, 1);
      ss2 += __shfl_xor(ss2, 2);
      ss2 += __shfl_xor(ss2, 4);
      ss2 += __shfl_xor(ss2, 8);
      if (lane == 0) red[w] = ss2;
      __syncthreads();
      float tot = 0.f;
      #pragma unroll
      for (int g = 0; g < 8; ++g) tot += red[g];
      float inv = 1.f / fmaxf(sqrtf(tot), 1e-12f);
      if (lane < 16) outb[(size_t)(T_ - 1) * D_] = uprev * inv;
    }
  } else {
    // ======================= streaming gemm producer ========================
    _Float16* smA[2] = {(_Float16*)smem, (_Float16*)(smem + 32768)};
    _Float16* smB[2] = {(_Float16*)(smem + 16384), (_Float16*)(smem + 49152)};

    const int wm = w >> 2, wn = w & 3;          // 2x4 wave grid: 128m x 64n
    const int fm = lane & 15, fq = lane >> 4;
    const int sw = fq ^ ((fm >> 1) & 3);        // bank-conflict deswizzle
    const f32x4 zero = {0.f, 0.f, 0.f, 0.f};

    const int cA0 = tid, cA1 = tid + 512;
    const int rA0 = cA0 >> 2, rA1 = cA1 >> 2;
    const int kA0 = (cA0 & 3) ^ ((rA0 >> 1) & 3);  // swizzled k-slot (staging)
    const int kA1 = (cA1 & 3) ^ ((rA1 >> 1) & 3);

    const int TOT = NCH_ * 128;                 // 4096 tiles (128/chunk)

    for (int job = (int)blockIdx.x - 32; job < TOT; job += 224) {
      const int g    = job >> 7;
      const int tile = job & 127;
      const int bn = tile & 63;
      const int bm = tile >> 6;

      _Float16* trans = (_Float16*)((char*)tbase + (size_t)(g % NB) * CHB);
      const int t0g = g * TC_;

      const int mc0 = bm * 256 + rA0, mc1 = bm * 256 + rA1;
      const int bb0 = mc0 >> 4, bb1 = mc1 >> 4;
      const _Float16* gA0 = h16 + ((size_t)bb0 * T_ + t0g + (mc0 & 15)) * H_ + kA0 * 8;
      const _Float16* gA1 = h16 + ((size_t)bb1 * T_ + t0g + (mc1 & 15)) * H_ + kA1 * 8;
      const _Float16* gB0 = w2t + ((size_t)bn * 256 + rA0) * H_ + kA0 * 8;
      const _Float16* gB1 = w2t + ((size_t)bn * 256 + rA1) * H_ + kA1 * 8;
      _Float16* lA0[2] = {&smA[0][cA0 * 8], &smA[1][cA0 * 8]};
      _Float16* lA1[2] = {&smA[0][cA1 * 8], &smA[1][cA1 * 8]};
      _Float16* lB0[2] = {&smB[0][cA0 * 8], &smB[1][cA0 * 8]};
      _Float16* lB1[2] = {&smB[0][cA1 * 8], &smB[1][cA1 * 8]};

      f32x4 acc[8][4];
      #pragma unroll
      for (int i = 0; i < 8; ++i)
        #pragma unroll
        for (int j = 0; j < 4; ++j) acc[i][j] = zero;

      // prologue: stage kt=0 into half 0
      glds(gA0, lA0[0]);
      glds(gA1, lA1[0]);
      glds(gB0, lB0[0]);
      glds(gB1, lB1[0]);

      #pragma unroll
      for (int kt = 0; kt < 8; ++kt) {
        __syncthreads();   // implicit vmcnt(0): glds(kt) landed; half free
        if (kt < 7) {
          const int h2 = (kt + 1) & 1;
          glds(gA0 + (kt + 1) * 32, lA0[h2]);
          glds(gA1 + (kt + 1) * 32, lA1[h2]);
          glds(gB0 + (kt + 1) * 32, lB0[h2]);
          glds(gB1 + (kt + 1) * 32, lB1[h2]);
        }
        const int hh = kt & 1;
        const _Float16* bA = smA[hh];
        const _Float16* bB = smB[hh];
        f16x8 af[8], bf[4];
        #pragma unroll
        for (int mt = 0; mt < 8; ++mt)
          af[mt] = *(const f16x8*)&bA[(wm * 128 + mt * 16 + fm) * 32 + sw * 8];
        #pragma unroll
        for (int nt = 0; nt < 4; ++nt)
          bf[nt] = *(const f16x8*)&bB[(wn * 64 + nt * 16 + fm) * 32 + sw * 8];
        #pragma unroll
        for (int mt = 0; mt < 8; ++mt)
          #pragma unroll
          for (int nt = 0; nt < 4; ++nt)
            acc[mt][nt] = __builtin_amdgcn_mfma_f32_16x16x32_f16(bf[nt], af[mt], acc[mt][nt], 0, 0, 0);
      }

      // bias decode (b2 direct, L2-hit) — hoisted before the gating wait
      const int colbase = bn * 256 + wn * 64;
      float bias[4][4];
      #pragma unroll
      for (int nt = 0; nt < 4; ++nt) {
        #pragma unroll
        for (int j = 0; j < 4; ++j) {
          int p = colbase + nt * 16 + fq * 4 + j;
          int ii = ((p >> 9) & 3) * 32 + ((p >> 7) & 3) * 8 + (p & 7);
          int jj = (p >> 11) * 16 + ((p >> 3) & 15);
          bias[nt][j] = b2[ii * 128 + jj];
        }
      }

      // back-pressure (buffer reuse) — gate only the overwrite
      if (g >= NB) {
        if (tid == 0) {
          while (__hip_atomic_load(&flags[512 + g - NB], __ATOMIC_RELAXED,
                                   __HIP_MEMORY_SCOPE_AGENT) < 32u)
            __builtin_amdgcn_s_sleep(8);
        }
        __syncthreads();
      }

      // epilogue: swapped-operand layout -> lane fm holds rows, 4 consec cols
      #pragma unroll
      for (int nt = 0; nt < 4; ++nt) {
        const int cb = nt * 16 + fq * 4;
        #pragma unroll
        for (int mt = 0; mt < 8; ++mt) {
          const long row = bm * 256 + wm * 128 + mt * 16 + fm;
          f16x4 v;
          #pragma unroll
          for (int j = 0; j < 4; ++j)
            v[j] = (_Float16)(acc[mt][nt][j] + bias[nt][j]);
          *(f16x4*)&trans[row * (long)N_ + colbase + cb] = v;
        }
      }
      __syncthreads();   // per-wave vmcnt(0): all stores drained
      if (tid == 0) {
        __threadfence();  // wbl2: cross-XCD release
        __hip_atomic_fetch_add(&flags[g * MT_ + bm], 1u, __ATOMIC_RELAXED,
                               __HIP_MEMORY_SCOPE_AGENT);
      }
    }
  }
}

// ---------------------------------------------------------------------------
extern "C" void kernel_launch(void* const* d_in, const int* in_sizes, int n_in,
                              void* d_out, int out_size, void* d_ws, size_t ws_size,
                              hipStream_t stream) {
  const float* actions = (const float*)d_in[0];   // [32,512,64]
  const float* init_s  = (const float*)d_in[1];   // [128]
  const float* w1      = (const float*)d_in[2];   // [64,256]
  const float* b1      = (const float*)d_in[3];   // [256]
  const float* w2      = (const float*)d_in[4];   // [256,16384]
  const float* b2      = (const float*)d_in[5];   // [16384]
  float* out = (float*)d_out;                     // [32,512,128]

  uint8_t* ws = (uint8_t*)d_ws;
  _Float16* w2t = (_Float16*)ws;                          // 8 MB
  _Float16* h16 = (_Float16*)(ws + ((size_t)8 << 20));    // 8 MB
  const size_t tb_off = (size_t)16 << 20;
  _Float16* tbase = (_Float16*)(ws + tb_off);

  // deepest chunk ring that fits (aux = 64KB dummy sink + 4KB flags after it)
  const size_t aux = 65536 + 4096;
  int NB = 2;
  if (tb_off + 4 * CHB + aux <= ws_size) NB = 4;
  else if (tb_off + 3 * CHB + aux <= ws_size) NB = 3;

  float*    dummyws = (float*)(ws + tb_off + (size_t)NB * CHB);
  unsigned* flags   = (unsigned*)(ws + tb_off + (size_t)NB * CHB + 65536);

  prep_kernel<<<1536, 256, 0, stream>>>(w2, w2t, actions, w1, b1, h16, flags);
  fused_kernel<<<256, 512, 0, stream>>>(h16, w2t, b2, tbase, init_s,
                                        out, dummyws, flags, NB);
}